// Round 5
// baseline (355.982 us; speedup 1.0000x reference)
//
#include <hip/hip_runtime.h>
#include <hip/hip_bf16.h>
#include <stdint.h>

// ---------------------------------------------------------------------------
// Swin-V2 window attention, MI355X (gfx950).
// R5: attn — static-max softmax (SMAX=48 folded into bias table, pad=-1e9),
//     no cross-lane ops in chunk loop, PV deferred 1 chunk (2-buf P in LDS),
//     grid 1536 (2 q-halves) -> 4 blocks/CU.
// ---------------------------------------------------------------------------

typedef __attribute__((ext_vector_type(4))) float f32x4;
typedef __attribute__((ext_vector_type(8))) short short8;

#define DIM   384
#define HEADS 12
#define NTOK  343
#define NPAD  352            // 22*16
#define BW    64             // windows*batch
#define MROWS (BW*NTOK)      // 21952
#define MPAD  22016          // 172*128
#define NN    (NTOK*NTOK)    // 117649
#define BPAD  352            // padded bias row length
#define LOG2E 1.44269504089f
#define SMAX  48.0f

__device__ __forceinline__ unsigned short f2bf(float f) {
  unsigned u = __float_as_uint(f);
  u += 0x7FFF + ((u >> 16) & 1);          // RNE
  return (unsigned short)(u >> 16);
}

// pack trunc-bf16: {hi[31:16], lo[31:16]}
__device__ __forceinline__ unsigned pk2bf(float lo, float hi) {
  return (__float_as_uint(hi) & 0xFFFF0000u) | (__float_as_uint(lo) >> 16);
}

__device__ __forceinline__ void gload_lds16(const void* g, void* l) {
  __builtin_amdgcn_global_load_lds(
      (const __attribute__((address_space(1))) void*)g,
      (__attribute__((address_space(3))) void*)l, 16, 0, 0);
}

// --------------------------- fp32 -> bf16 convert ---------------------------
__global__ __launch_bounds__(256) void cvt_bf16(const float* __restrict__ in,
                                                unsigned short* __restrict__ out,
                                                long nvalid, long ntotal) {
  long i = ((long)blockIdx.x * 256 + threadIdx.x) * 8;
  if (i >= ntotal) return;
  short8 o;
  if (i < nvalid) {
    const float4* p = (const float4*)(in + i);
    float4 a = p[0], b = p[1];
    o[0] = (short)f2bf(a.x); o[1] = (short)f2bf(a.y);
    o[2] = (short)f2bf(a.z); o[3] = (short)f2bf(a.w);
    o[4] = (short)f2bf(b.x); o[5] = (short)f2bf(b.y);
    o[6] = (short)f2bf(b.z); o[7] = (short)f2bf(b.w);
  } else {
    o = (short8)0;                         // zero-fill M padding rows
  }
  *(short8*)(out + i) = o;
}

// --------------------------- CPB MLP (2197 x 12) ----------------------------
__global__ __launch_bounds__(64) void cpb_tab(const float* __restrict__ tbl,
                                              const float* __restrict__ w1,
                                              const float* __restrict__ b1,
                                              const float* __restrict__ w2,
                                              float* __restrict__ btab) {
  const int r = blockIdx.x, lane = threadIdx.x;
  const float t0 = tbl[r*3], t1 = tbl[r*3+1], t2 = tbl[r*3+2];
  float acc[12];
#pragma unroll
  for (int hh = 0; hh < 12; ++hh) acc[hh] = 0.f;
  for (int u = 0; u < 8; ++u) {
    const int j = lane * 8 + u;
    const float hd = fmaxf(w1[j*3]*t0 + w1[j*3+1]*t1 + w1[j*3+2]*t2 + b1[j], 0.f);
#pragma unroll
    for (int hh = 0; hh < 12; ++hh) acc[hh] += hd * w2[hh*512 + j];
  }
#pragma unroll
  for (int hh = 0; hh < 12; ++hh) {
    float v = acc[hh];
    for (int msk = 1; msk < 64; msk <<= 1) v += __shfl_xor(v, msk);
    if (lane == 0) btab[r*12 + hh] = v;
  }
}

// -- bias gather: (12,343,352) = LOG2E*16*sigmoid - SMAX; pad cols = -1e9 ----
__global__ __launch_bounds__(256) void bias_gather(const float* __restrict__ btab,
                                                   const int* __restrict__ ridx,
                                                   float* __restrict__ bfull) {
  const int blk = blockIdx.x;              // hh*343 + i
  const int hh = blk / NTOK, i = blk % NTOK;
  for (int j = threadIdx.x; j < BPAD; j += 256) {
    float o = -1e9f;                       // pad: kills k>=343 (and garbage mask)
    if (j < NTOK) {
      const int idx = ridx[i*NTOK + j];
      const float v = btab[idx*12 + hh];
      o = LOG2E * 16.f / (1.f + __expf(-v)) - SMAX;
    }
    bfull[(size_t)blk*BPAD + j] = o;
  }
}

// ------------------------------- GEMM (bf16) --------------------------------
// C(128x128) = A(row-major MxK) * B(N,K)^T. BK=64, 4 waves (2x2 of 64x64).
// LDS XOR swizzle applied via pre-swizzled global source (guide rule 21).
// MODE 0: qkv epilogue (bias, cosine-norm, scale*LOG2E fold, bf16 q/k + v^T)
// MODE 1: proj epilogue (+proj_b, fp32 out)
template<int MODE>
__global__ __launch_bounds__(256, 2) void gemm_k(
    const unsigned short* __restrict__ A, const unsigned short* __restrict__ B,
    unsigned short* __restrict__ o_qn, unsigned short* __restrict__ o_kn,
    unsigned short* __restrict__ o_vT,
    const float* __restrict__ q_bias, const float* __restrict__ v_bias,
    const float* __restrict__ lsc,
    float* __restrict__ o_out, const float* __restrict__ proj_b) {
  __shared__ alignas(16) uint8_t lds[32768];   // A: [0,16K) B: [16K,32K)
  const int tid = threadIdx.x, wave = tid >> 6, lane = tid & 63;
  const int row0 = blockIdx.x * 128, col0 = blockIdx.y * 128;
  const int wm = wave & 1, wn = wave >> 1;
  const int l15 = lane & 15, lq = lane >> 4;
  f32x4 acc[4][4];
#pragma unroll
  for (int i = 0; i < 4; ++i)
#pragma unroll
    for (int j = 0; j < 4; ++j) acc[i][j] = (f32x4)0.f;

  const int stg_row = wave * 8 + (lane >> 3);
  const int srcblk = (lane & 7) ^ (lane >> 3);   // pre-swizzled source block

  for (int kt = 0; kt < 6; ++kt) {
    const int k0 = kt * 64;
#pragma unroll
    for (int c = 0; c < 4; ++c) {
      const int row = c * 32 + stg_row;
      gload_lds16(A + (size_t)(row0 + row) * DIM + k0 + srcblk * 8,
                  lds + c * 4096 + wave * 1024);
      gload_lds16(B + (size_t)(col0 + row) * DIM + k0 + srcblk * 8,
                  lds + 16384 + c * 4096 + wave * 1024);
    }
    __syncthreads();
#pragma unroll
    for (int s = 0; s < 2; ++s) {
      short8 af[4], bfr[4];
#pragma unroll
      for (int i = 0; i < 4; ++i) {
        const int r = wm * 64 + i * 16 + l15;
        af[i] = *(const short8*)(lds + r * 128 + (((s * 4) | lq) ^ (r & 7)) * 16);
        const int cc = wn * 64 + i * 16 + l15;
        bfr[i] = *(const short8*)(lds + 16384 + cc * 128 + (((s * 4) | lq) ^ (cc & 7)) * 16);
      }
#pragma unroll
      for (int i = 0; i < 4; ++i)
#pragma unroll
        for (int j = 0; j < 4; ++j)
          acc[i][j] = __builtin_amdgcn_mfma_f32_16x16x32_bf16(af[i], bfr[j], acc[i][j], 0, 0, 0);
    }
    __syncthreads();
  }

  if (MODE == 0) {
    // C cols = [q(0:384) | k(384:768) | v(768:1152)]; each 32-col chunk = one head slice
#pragma unroll
    for (int i = 0; i < 4; ++i) {
      const int gr0 = row0 + wm * 64 + i * 16 + lq * 4;
#pragma unroll
      for (int p = 0; p < 2; ++p) {
        f32x4 c0 = acc[i][2 * p], c1 = acc[i][2 * p + 1];
        const int gcb = col0 + wn * 64 + p * 32;
        const int which = gcb / DIM, rem = gcb % DIM, hh = rem / 32;
        float b0 = 0.f, b1 = 0.f;
        if (which == 0) { b0 = q_bias[rem + l15]; b1 = q_bias[rem + l15 + 16]; }
        else if (which == 2) { b0 = v_bias[rem + l15]; b1 = v_bias[rem + l15 + 16]; }
#pragma unroll
        for (int r = 0; r < 4; ++r) { c0[r] += b0; c1[r] += b1; }
        float mult[4] = {1.f, 1.f, 1.f, 1.f};
        if (which < 2) {                     // cosine-norm q,k (row = 32 cols in this chunk)
          f32x4 ss;
#pragma unroll
          for (int r = 0; r < 4; ++r) ss[r] = c0[r] * c0[r] + c1[r] * c1[r];
#pragma unroll
          for (int msk = 1; msk < 16; msk <<= 1) {
#pragma unroll
            for (int r = 0; r < 4; ++r) ss[r] += __shfl_xor(ss[r], msk);
          }
          float sc = 1.f;
          if (which == 0)                    // fold scale AND log2(e) into q
            sc = __expf(fminf(lsc[hh], 4.6051701860f)) * LOG2E;
#pragma unroll
          for (int r = 0; r < 4; ++r) mult[r] = sc / fmaxf(sqrtf(ss[r]), 1e-12f);
        }
#pragma unroll
        for (int r = 0; r < 4; ++r) {
          const int gr = gr0 + r;
          if (gr >= MROWS) continue;
          const int b = gr / NTOK, nt = gr % NTOK;
          const unsigned short v0 = f2bf(c0[r] * mult[r]);
          const unsigned short v1 = f2bf(c1[r] * mult[r]);
          if (which == 0) {
            const size_t base = ((size_t)(b * HEADS + hh) * NTOK + nt) * 32 + l15;
            o_qn[base] = v0; o_qn[base + 16] = v1;
          } else if (which == 1) {
            const size_t base = ((size_t)(b * HEADS + hh) * NTOK + nt) * 32 + l15;
            o_kn[base] = v0; o_kn[base + 16] = v1;
          } else {                            // v transposed: (b,h,32,NPAD)
            const size_t base = ((size_t)(b * HEADS + hh) * 32 + l15) * NPAD + nt;
            o_vT[base] = v0; o_vT[base + (size_t)16 * NPAD] = v1;
          }
        }
      }
    }
  } else {
#pragma unroll
    for (int i = 0; i < 4; ++i) {
      const int gr0 = row0 + wm * 64 + i * 16 + lq * 4;
#pragma unroll
      for (int j = 0; j < 4; ++j) {
        const int gc = col0 + wn * 64 + j * 16 + l15;
        const float pb = proj_b[gc];
#pragma unroll
        for (int r = 0; r < 4; ++r) {
          const int gr = gr0 + r;
          if (gr < MROWS) o_out[(size_t)gr * DIM + gc] = acc[i][j][r] + pb;
        }
      }
    }
  }
}

// ------------------------------- attention ---------------------------------
// 1 block = (window b, head h, q-half). Swapped QK^T (mfma(K,Q)); static-max
// softmax in log2 domain (SMAX folded into bias, pad=-1e9 kills tail) -> zero
// cross-lane ops in chunk loop. PV deferred 1 chunk via double-buffered P.
// K in LDS; V/bias/mask/K-frag prefetched 1 chunk ahead into regs.
__global__ __launch_bounds__(256, 4) void attn_k(
    const unsigned short* __restrict__ qn, const unsigned short* __restrict__ kn,
    const unsigned short* __restrict__ vT, const float* __restrict__ bfull,
    const float* __restrict__ mask, unsigned short* __restrict__ out1) {
  __shared__ alignas(16) uint8_t lds[38400]; // K:[0,28160) P: 4 waves x 2 x 1280
  const int g = blockIdx.x;
  // XCD swizzle: 24 blocks (12 heads x 2 halves) of one window per XCD
  const int idx = g >> 3;
  const int b = (g & 7) * 8 + idx / 24;
  const int r24 = idx % 24;
  const int hh = r24 >> 1, half = r24 & 1;
  const int bh = b * HEADS + hh;
  const int tid = threadIdx.x;

  for (int r = tid; r < NPAD; r += 256) {
    uint4* dst = (uint4*)(lds + r * 80);
    if (r < NTOK) {
      const uint4* src = (const uint4*)(kn + ((size_t)bh * NTOK + r) * 32);
      dst[0] = src[0]; dst[1] = src[1]; dst[2] = src[2]; dst[3] = src[3];
    } else {
      uint4 z = make_uint4(0, 0, 0, 0);
      dst[0] = z; dst[1] = z; dst[2] = z; dst[3] = z;
    }
  }
  __syncthreads();

  const int wave = tid >> 6, lane = tid & 63;
  const int l15 = lane & 15, lq = lane >> 4;
  uint8_t* pb0 = lds + 28160 + wave * 2560;     // P parity 0 (16 x 80B)
  uint8_t* pb1 = pb0 + 1280;                    // P parity 1

  const unsigned short* vrow0 = vT + ((size_t)bh * 32 + l15) * NPAD;      // d=l15
  const unsigned short* vrow1 = vT + ((size_t)bh * 32 + 16 + l15) * NPAD; // d=l15+16

  for (int t = wave; t < 11; t += 4) {
    const int q0 = (half * 11 + t) * 16;
    const int qc = min(q0 + l15, NTOK - 1);     // clamp pad q-rows
    const short8 aq = *(const short8*)(qn + ((size_t)bh * NTOK + qc) * 32 + lq * 8);
    const float* brow = bfull + ((size_t)hh * NTOK + qc) * BPAD;
    const float* mrow = mask + (size_t)b * NN + (size_t)qc * NTOK;

    f32x4 o0 = (f32x4)0.f, o1 = (f32x4)0.f;
    float l_run = 0.f;

    f32x4 pbA[2], pbB[2];          // bias (log2, incl -SMAX; pad=-1e9)
    float pmA[2][4], pmB[2][4];    // mask
    short8 kf0[2], kf1[2], vf0[2], vf1[2];

    // prologue: chunk 0 bias/mask/K
    pbA[0] = *(const f32x4*)(brow + lq * 4);
    pbB[0] = *(const f32x4*)(brow + 16 + lq * 4);
#pragma unroll
    for (int r = 0; r < 4; ++r) {
      pmA[0][r] = mrow[lq * 4 + r];
      pmB[0][r] = mrow[16 + lq * 4 + r];
    }
    kf0[0] = *(const short8*)(lds + l15 * 80 + lq * 16);
    kf1[0] = *(const short8*)(lds + (16 + l15) * 80 + lq * 16);

#pragma unroll
    for (int c = 0; c <= 10; ++c) {
      const int cur = c & 1, nxt = cur ^ 1;
      const int kc = c * 32;
      // V(c) -> slot cur (consumed by deferred PV at iter c+1)
      vf0[cur] = *(const short8*)(vrow0 + kc + lq * 8);
      vf1[cur] = *(const short8*)(vrow1 + kc + lq * 8);
      if (c < 10) {                 // prefetch chunk c+1 bias/mask/K
        const int k2 = kc + 32;
        pbA[nxt] = *(const f32x4*)(brow + k2 + lq * 4);
        pbB[nxt] = *(const f32x4*)(brow + k2 + 16 + lq * 4);
#pragma unroll
        for (int r = 0; r < 4; ++r) {
          pmA[nxt][r] = mrow[k2 + lq * 4 + r];
          const int kk = k2 + 16 + lq * 4 + r;
          pmB[nxt][r] = mrow[(c == 9 && kk >= NTOK) ? 0 : kk];  // in-bounds only; bias=-1e9 kills it
        }
        kf0[nxt] = *(const short8*)(lds + (k2 + l15) * 80 + lq * 16);
        kf1[nxt] = *(const short8*)(lds + (k2 + 16 + l15) * 80 + lq * 16);
      }
      // swapped QK^T: D[k = lq*4+r (+16), q = l15]  (scale*log2e folded in q)
      f32x4 s0 = __builtin_amdgcn_mfma_f32_16x16x32_bf16(kf0[cur], aq, (f32x4)0.f, 0, 0, 0);
      f32x4 s1 = __builtin_amdgcn_mfma_f32_16x16x32_bf16(kf1[cur], aq, (f32x4)0.f, 0, 0, 0);
      float p0[4], p1[4], ps = 0.f;
#pragma unroll
      for (int r = 0; r < 4; ++r) {
        p0[r] = exp2f(s0[r] + fmaf(pmA[cur][r], LOG2E, pbA[cur][r]));
        p1[r] = exp2f(s1[r] + fmaf(pmB[cur][r], LOG2E, pbB[cur][r]));
        ps += p0[r] + p1[r];
      }
      l_run += ps;
      // pack P (trunc bf16) -> LDS parity cur
      uint8_t* pw = (cur ? pb1 : pb0) + l15 * 80;
      *(uint2*)(pw + lq * 8)      = make_uint2(pk2bf(p0[0], p0[1]), pk2bf(p0[2], p0[3]));
      *(uint2*)(pw + 32 + lq * 8) = make_uint2(pk2bf(p1[0], p1[1]), pk2bf(p1[2], p1[3]));
      if (c > 0) {                  // deferred PV for chunk c-1 (parity nxt)
        const short8 pf = *(const short8*)((nxt ? pb1 : pb0) + l15 * 80 + lq * 16);
        o0 = __builtin_amdgcn_mfma_f32_16x16x32_bf16(pf, vf0[nxt], o0, 0, 0, 0);
        o1 = __builtin_amdgcn_mfma_f32_16x16x32_bf16(pf, vf1[nxt], o1, 0, 0, 0);
      }
    }
    {                               // PV for chunk 10 (parity 0)
      const short8 pf = *(const short8*)(pb0 + l15 * 80 + lq * 16);
      o0 = __builtin_amdgcn_mfma_f32_16x16x32_bf16(pf, vf0[0], o0, 0, 0, 0);
      o1 = __builtin_amdgcn_mfma_f32_16x16x32_bf16(pf, vf1[0], o1, 0, 0, 0);
    }
    // row-sum over 4 lq groups, broadcast to o-holder lanes (once per tile)
    l_run += __shfl_xor(l_run, 16);
    l_run += __shfl_xor(l_run, 32);
    const float invl = 1.f / l_run;
    float ir[4];
#pragma unroll
    for (int r = 0; r < 4; ++r) ir[r] = __shfl(invl, lq * 4 + r);
#pragma unroll
    for (int r = 0; r < 4; ++r) {
      const int q = q0 + lq * 4 + r;
      if (q < NTOK) {
        const size_t base = ((size_t)b * NTOK + q) * DIM + hh * 32 + l15;
        out1[base]      = f2bf(o0[r] * ir[r]);
        out1[base + 16] = f2bf(o1[r] * ir[r]);
      }
    }
  }
}

// ------------------------------- host launch --------------------------------
extern "C" void kernel_launch(void* const* d_in, const int* in_sizes, int n_in,
                              void* d_out, int out_size, void* d_ws, size_t ws_size,
                              hipStream_t stream) {
  const float* x      = (const float*)d_in[0];
  const float* mask   = (const float*)d_in[1];
  const float* qkv_w  = (const float*)d_in[2];
  const float* q_bias = (const float*)d_in[3];
  const float* v_bias = (const float*)d_in[4];
  const float* lsc    = (const float*)d_in[5];
  const float* cpb_w1 = (const float*)d_in[6];
  const float* cpb_b1 = (const float*)d_in[7];
  const float* cpb_w2 = (const float*)d_in[8];
  const float* proj_w = (const float*)d_in[9];
  const float* proj_b = (const float*)d_in[10];
  const float* rtab   = (const float*)d_in[11];
  const int*   ridx   = (const int*)d_in[12];
  float* out = (float*)d_out;
  uint8_t* ws = (uint8_t*)d_ws;

  size_t o = 0;
  auto alloc = [&](size_t bytes) { size_t r = o; o += (bytes + 255) & ~(size_t)255; return r; };
  const size_t off_xb  = alloc((size_t)MPAD * DIM * 2);   // also reused as o1b
  const size_t off_qwb = alloc((size_t)1152 * DIM * 2);
  const size_t off_pwb = alloc((size_t)DIM * DIM * 2);
  const size_t off_qnb = alloc((size_t)BW * HEADS * NTOK * 32 * 2);
  const size_t off_knb = alloc((size_t)BW * HEADS * NTOK * 32 * 2);
  const size_t off_vTb = alloc((size_t)BW * HEADS * 32 * NPAD * 2);
  const size_t off_btab  = alloc((size_t)2197 * 12 * 4);
  const size_t off_bfull = alloc((size_t)HEADS * NTOK * BPAD * 4);
  (void)in_sizes; (void)n_in; (void)out_size;

  if (ws_size < o) {   // diagnostic sentinel: clean fail (absmax ~= max|ref|)
    hipMemsetAsync(d_out, 0, (size_t)out_size * 4, stream);
    return;
  }

  unsigned short* xb  = (unsigned short*)(ws + off_xb);
  unsigned short* o1b = xb;                      // alias: xb dead after gemm<0>
  unsigned short* qwb = (unsigned short*)(ws + off_qwb);
  unsigned short* pwb = (unsigned short*)(ws + off_pwb);
  unsigned short* qnb = (unsigned short*)(ws + off_qnb);
  unsigned short* knb = (unsigned short*)(ws + off_knb);
  unsigned short* vTb = (unsigned short*)(ws + off_vTb);
  float* btab  = (float*)(ws + off_btab);
  float* bfull = (float*)(ws + off_bfull);

  cvt_bf16<<<(long)MPAD * DIM / 8 / 256, 256, 0, stream>>>(x, xb, (long)MROWS * DIM, (long)MPAD * DIM);
  cvt_bf16<<<1152 * DIM / 8 / 256, 256, 0, stream>>>(qkv_w, qwb, 1152L * DIM, 1152L * DIM);
  cvt_bf16<<<DIM * DIM / 8 / 256, 256, 0, stream>>>(proj_w, pwb, (long)DIM * DIM, (long)DIM * DIM);
  cpb_tab<<<2197, 64, 0, stream>>>(rtab, cpb_w1, cpb_b1, cpb_w2, btab);
  bias_gather<<<HEADS * NTOK, 256, 0, stream>>>(btab, ridx, bfull);
  gemm_k<0><<<dim3(MPAD / 128, 1152 / 128), 256, 0, stream>>>(
      xb, qwb, qnb, knb, vTb, q_bias, v_bias, lsc, nullptr, nullptr);
  attn_k<<<2 * BW * HEADS, 256, 0, stream>>>(qnb, knb, vTb, bfull, mask, o1b);
  gemm_k<1><<<dim3(MPAD / 128, DIM / 128), 256, 0, stream>>>(
      o1b, pwb, nullptr, nullptr, nullptr, nullptr, nullptr, nullptr, out, proj_b);
}

// Round 7
// 322.789 us; speedup vs baseline: 1.1028x; 1.1028x over previous
//
#include <hip/hip_runtime.h>
#include <hip/hip_bf16.h>
#include <stdint.h>

// ---------------------------------------------------------------------------
// Swin-V2 window attention, MI355X (gfx950).
// R6: attn — revert q-split (768 blocks, 22 tiles/block, 3 blk/CU exact);
//     keep static-max log2 softmax (SMAX in bias table, pad=-1e9) + deferred
//     PV; add depth-2 bias/mask prefetch (copy-out ring, const idx under
//     unroll); V^T rows paired (2*l15, 2*l15+1) -> single u32 output store.
// R7: identical resubmit (R6 failure was GPU acquisition timeout, not kernel).
// ---------------------------------------------------------------------------

typedef __attribute__((ext_vector_type(4))) float f32x4;
typedef __attribute__((ext_vector_type(8))) short short8;

#define DIM   384
#define HEADS 12
#define NTOK  343
#define NPAD  352            // 22*16
#define BW    64             // windows*batch
#define MROWS (BW*NTOK)      // 21952
#define MPAD  22016          // 172*128
#define NN    (NTOK*NTOK)    // 117649
#define BPAD  352            // padded bias row length
#define LOG2E 1.44269504089f
#define SMAX  48.0f

__device__ __forceinline__ unsigned short f2bf(float f) {
  unsigned u = __float_as_uint(f);
  u += 0x7FFF + ((u >> 16) & 1);          // RNE
  return (unsigned short)(u >> 16);
}

// pack trunc-bf16: {hi[31:16], lo[31:16]}
__device__ __forceinline__ unsigned pk2bf(float lo, float hi) {
  return (__float_as_uint(hi) & 0xFFFF0000u) | (__float_as_uint(lo) >> 16);
}

__device__ __forceinline__ void gload_lds16(const void* g, void* l) {
  __builtin_amdgcn_global_load_lds(
      (const __attribute__((address_space(1))) void*)g,
      (__attribute__((address_space(3))) void*)l, 16, 0, 0);
}

// --------------------------- fp32 -> bf16 convert ---------------------------
__global__ __launch_bounds__(256) void cvt_bf16(const float* __restrict__ in,
                                                unsigned short* __restrict__ out,
                                                long nvalid, long ntotal) {
  long i = ((long)blockIdx.x * 256 + threadIdx.x) * 8;
  if (i >= ntotal) return;
  short8 o;
  if (i < nvalid) {
    const float4* p = (const float4*)(in + i);
    float4 a = p[0], b = p[1];
    o[0] = (short)f2bf(a.x); o[1] = (short)f2bf(a.y);
    o[2] = (short)f2bf(a.z); o[3] = (short)f2bf(a.w);
    o[4] = (short)f2bf(b.x); o[5] = (short)f2bf(b.y);
    o[6] = (short)f2bf(b.z); o[7] = (short)f2bf(b.w);
  } else {
    o = (short8)0;                         // zero-fill M padding rows
  }
  *(short8*)(out + i) = o;
}

// --------------------------- CPB MLP (2197 x 12) ----------------------------
__global__ __launch_bounds__(64) void cpb_tab(const float* __restrict__ tbl,
                                              const float* __restrict__ w1,
                                              const float* __restrict__ b1,
                                              const float* __restrict__ w2,
                                              float* __restrict__ btab) {
  const int r = blockIdx.x, lane = threadIdx.x;
  const float t0 = tbl[r*3], t1 = tbl[r*3+1], t2 = tbl[r*3+2];
  float acc[12];
#pragma unroll
  for (int hh = 0; hh < 12; ++hh) acc[hh] = 0.f;
  for (int u = 0; u < 8; ++u) {
    const int j = lane * 8 + u;
    const float hd = fmaxf(w1[j*3]*t0 + w1[j*3+1]*t1 + w1[j*3+2]*t2 + b1[j], 0.f);
#pragma unroll
    for (int hh = 0; hh < 12; ++hh) acc[hh] += hd * w2[hh*512 + j];
  }
#pragma unroll
  for (int hh = 0; hh < 12; ++hh) {
    float v = acc[hh];
    for (int msk = 1; msk < 64; msk <<= 1) v += __shfl_xor(v, msk);
    if (lane == 0) btab[r*12 + hh] = v;
  }
}

// -- bias gather: (12,343,352) = LOG2E*16*sigmoid - SMAX; pad cols = -1e9 ----
__global__ __launch_bounds__(256) void bias_gather(const float* __restrict__ btab,
                                                   const int* __restrict__ ridx,
                                                   float* __restrict__ bfull) {
  const int blk = blockIdx.x;              // hh*343 + i
  const int hh = blk / NTOK, i = blk % NTOK;
  for (int j = threadIdx.x; j < BPAD; j += 256) {
    float o = -1e9f;                       // pad: kills k>=343 (and garbage mask)
    if (j < NTOK) {
      const int idx = ridx[i*NTOK + j];
      const float v = btab[idx*12 + hh];
      o = LOG2E * 16.f / (1.f + __expf(-v)) - SMAX;
    }
    bfull[(size_t)blk*BPAD + j] = o;
  }
}

// ------------------------------- GEMM (bf16) --------------------------------
// C(128x128) = A(row-major MxK) * B(N,K)^T. BK=64, 4 waves (2x2 of 64x64).
// LDS XOR swizzle applied via pre-swizzled global source (guide rule 21).
// MODE 0: qkv epilogue (bias, cosine-norm, scale*LOG2E fold, bf16 q/k + v^T)
// MODE 1: proj epilogue (+proj_b, fp32 out)
template<int MODE>
__global__ __launch_bounds__(256, 2) void gemm_k(
    const unsigned short* __restrict__ A, const unsigned short* __restrict__ B,
    unsigned short* __restrict__ o_qn, unsigned short* __restrict__ o_kn,
    unsigned short* __restrict__ o_vT,
    const float* __restrict__ q_bias, const float* __restrict__ v_bias,
    const float* __restrict__ lsc,
    float* __restrict__ o_out, const float* __restrict__ proj_b) {
  __shared__ alignas(16) uint8_t lds[32768];   // A: [0,16K) B: [16K,32K)
  const int tid = threadIdx.x, wave = tid >> 6, lane = tid & 63;
  const int row0 = blockIdx.x * 128, col0 = blockIdx.y * 128;
  const int wm = wave & 1, wn = wave >> 1;
  const int l15 = lane & 15, lq = lane >> 4;
  f32x4 acc[4][4];
#pragma unroll
  for (int i = 0; i < 4; ++i)
#pragma unroll
    for (int j = 0; j < 4; ++j) acc[i][j] = (f32x4)0.f;

  const int stg_row = wave * 8 + (lane >> 3);
  const int srcblk = (lane & 7) ^ (lane >> 3);   // pre-swizzled source block

  for (int kt = 0; kt < 6; ++kt) {
    const int k0 = kt * 64;
#pragma unroll
    for (int c = 0; c < 4; ++c) {
      const int row = c * 32 + stg_row;
      gload_lds16(A + (size_t)(row0 + row) * DIM + k0 + srcblk * 8,
                  lds + c * 4096 + wave * 1024);
      gload_lds16(B + (size_t)(col0 + row) * DIM + k0 + srcblk * 8,
                  lds + 16384 + c * 4096 + wave * 1024);
    }
    __syncthreads();
#pragma unroll
    for (int s = 0; s < 2; ++s) {
      short8 af[4], bfr[4];
#pragma unroll
      for (int i = 0; i < 4; ++i) {
        const int r = wm * 64 + i * 16 + l15;
        af[i] = *(const short8*)(lds + r * 128 + (((s * 4) | lq) ^ (r & 7)) * 16);
        const int cc = wn * 64 + i * 16 + l15;
        bfr[i] = *(const short8*)(lds + 16384 + cc * 128 + (((s * 4) | lq) ^ (cc & 7)) * 16);
      }
#pragma unroll
      for (int i = 0; i < 4; ++i)
#pragma unroll
        for (int j = 0; j < 4; ++j)
          acc[i][j] = __builtin_amdgcn_mfma_f32_16x16x32_bf16(af[i], bfr[j], acc[i][j], 0, 0, 0);
    }
    __syncthreads();
  }

  if (MODE == 0) {
    // C cols = [q(0:384) | k(384:768) | v(768:1152)]; each 32-col chunk = one head slice
#pragma unroll
    for (int i = 0; i < 4; ++i) {
      const int gr0 = row0 + wm * 64 + i * 16 + lq * 4;
#pragma unroll
      for (int p = 0; p < 2; ++p) {
        f32x4 c0 = acc[i][2 * p], c1 = acc[i][2 * p + 1];
        const int gcb = col0 + wn * 64 + p * 32;
        const int which = gcb / DIM, rem = gcb % DIM, hh = rem / 32;
        float b0 = 0.f, b1 = 0.f;
        if (which == 0) { b0 = q_bias[rem + l15]; b1 = q_bias[rem + l15 + 16]; }
        else if (which == 2) { b0 = v_bias[rem + l15]; b1 = v_bias[rem + l15 + 16]; }
#pragma unroll
        for (int r = 0; r < 4; ++r) { c0[r] += b0; c1[r] += b1; }
        float mult[4] = {1.f, 1.f, 1.f, 1.f};
        if (which < 2) {                     // cosine-norm q,k (row = 32 cols in this chunk)
          f32x4 ss;
#pragma unroll
          for (int r = 0; r < 4; ++r) ss[r] = c0[r] * c0[r] + c1[r] * c1[r];
#pragma unroll
          for (int msk = 1; msk < 16; msk <<= 1) {
#pragma unroll
            for (int r = 0; r < 4; ++r) ss[r] += __shfl_xor(ss[r], msk);
          }
          float sc = 1.f;
          if (which == 0)                    // fold scale AND log2(e) into q
            sc = __expf(fminf(lsc[hh], 4.6051701860f)) * LOG2E;
#pragma unroll
          for (int r = 0; r < 4; ++r) mult[r] = sc / fmaxf(sqrtf(ss[r]), 1e-12f);
        }
#pragma unroll
        for (int r = 0; r < 4; ++r) {
          const int gr = gr0 + r;
          if (gr >= MROWS) continue;
          const int b = gr / NTOK, nt = gr % NTOK;
          const unsigned short v0 = f2bf(c0[r] * mult[r]);
          const unsigned short v1 = f2bf(c1[r] * mult[r]);
          if (which == 0) {
            const size_t base = ((size_t)(b * HEADS + hh) * NTOK + nt) * 32 + l15;
            o_qn[base] = v0; o_qn[base + 16] = v1;
          } else if (which == 1) {
            const size_t base = ((size_t)(b * HEADS + hh) * NTOK + nt) * 32 + l15;
            o_kn[base] = v0; o_kn[base + 16] = v1;
          } else {                            // v transposed: (b,h,32,NPAD)
            const size_t base = ((size_t)(b * HEADS + hh) * 32 + l15) * NPAD + nt;
            o_vT[base] = v0; o_vT[base + (size_t)16 * NPAD] = v1;
          }
        }
      }
    }
  } else {
#pragma unroll
    for (int i = 0; i < 4; ++i) {
      const int gr0 = row0 + wm * 64 + i * 16 + lq * 4;
#pragma unroll
      for (int j = 0; j < 4; ++j) {
        const int gc = col0 + wn * 64 + j * 16 + l15;
        const float pb = proj_b[gc];
#pragma unroll
        for (int r = 0; r < 4; ++r) {
          const int gr = gr0 + r;
          if (gr < MROWS) o_out[(size_t)gr * DIM + gc] = acc[i][j][r] + pb;
        }
      }
    }
  }
}

// ------------------------------- attention ---------------------------------
// 1 block = (window b, head h), 22 q-tiles / 4 waves. Swapped QK^T; static-max
// log2 softmax (zero cross-lane in chunk loop); PV deferred 1 chunk (2-buf P).
// Depth-2 reg prefetch of bias/mask; V/K-frag 1 ahead. V^T rows paired
// (2*l15, 2*l15+1) so each lane's outputs are adjacent -> u32 stores.
__global__ __launch_bounds__(256, 3) void attn_k(
    const unsigned short* __restrict__ qn, const unsigned short* __restrict__ kn,
    const unsigned short* __restrict__ vT, const float* __restrict__ bfull,
    const float* __restrict__ mask, unsigned short* __restrict__ out1) {
  __shared__ alignas(16) uint8_t lds[38400]; // K:[0,28160) P: 4 waves x 2 x 1280
  const int g = blockIdx.x;
  // XCD swizzle: all 12 heads of one window land on the same XCD (mask L2-local)
  const int b = (g & 7) * 8 + (g >> 3) / HEADS;
  const int hh = (g >> 3) % HEADS;
  const int bh = b * HEADS + hh;
  const int tid = threadIdx.x;

  for (int r = tid; r < NPAD; r += 256) {
    uint4* dst = (uint4*)(lds + r * 80);
    if (r < NTOK) {
      const uint4* src = (const uint4*)(kn + ((size_t)bh * NTOK + r) * 32);
      dst[0] = src[0]; dst[1] = src[1]; dst[2] = src[2]; dst[3] = src[3];
    } else {
      uint4 z = make_uint4(0, 0, 0, 0);
      dst[0] = z; dst[1] = z; dst[2] = z; dst[3] = z;
    }
  }
  __syncthreads();

  const int wave = tid >> 6, lane = tid & 63;
  const int l15 = lane & 15, lq = lane >> 4;
  uint8_t* pb0 = lds + 28160 + wave * 2560;     // P parity 0 (16 x 80B)
  uint8_t* pb1 = pb0 + 1280;                    // P parity 1

  // paired V rows: lane column n=l15 carries d=2*l15 (o0) and d=2*l15+1 (o1)
  const unsigned short* vrow0 = vT + ((size_t)bh * 32 + 2 * l15) * NPAD;
  const unsigned short* vrow1 = vT + ((size_t)bh * 32 + 2 * l15 + 1) * NPAD;

  for (int t = wave; t < 22; t += 4) {
    const int q0 = t * 16;
    const int qc = min(q0 + l15, NTOK - 1);     // clamp pad q-rows
    const short8 aq = *(const short8*)(qn + ((size_t)bh * NTOK + qc) * 32 + lq * 8);
    const float* brow = bfull + ((size_t)hh * NTOK + qc) * BPAD;
    const float* mrow = mask + (size_t)b * NN + (size_t)qc * NTOK;

    f32x4 o0 = (f32x4)0.f, o1 = (f32x4)0.f;
    float l_run = 0.f;

    f32x4 pbA[2], pbB[2];          // bias (log2, incl -SMAX; pad=-1e9), depth-2
    float pmA[2][4], pmB[2][4];    // mask, depth-2
    short8 kf0[2], kf1[2], vf0[2], vf1[2];

    // prologue: bias/mask chunks 0,1; K chunk 0; V chunk 0
    pbA[0] = *(const f32x4*)(brow + lq * 4);
    pbB[0] = *(const f32x4*)(brow + 16 + lq * 4);
    pbA[1] = *(const f32x4*)(brow + 32 + lq * 4);
    pbB[1] = *(const f32x4*)(brow + 48 + lq * 4);
#pragma unroll
    for (int r = 0; r < 4; ++r) {
      pmA[0][r] = mrow[lq * 4 + r];
      pmB[0][r] = mrow[16 + lq * 4 + r];
      pmA[1][r] = mrow[32 + lq * 4 + r];
      pmB[1][r] = mrow[48 + lq * 4 + r];
    }
    kf0[0] = *(const short8*)(lds + l15 * 80 + lq * 16);
    kf1[0] = *(const short8*)(lds + (16 + l15) * 80 + lq * 16);
    vf0[0] = *(const short8*)(vrow0 + lq * 8);
    vf1[0] = *(const short8*)(vrow1 + lq * 8);

#pragma unroll
    for (int c = 0; c <= 10; ++c) {
      const int cur = c & 1, nxt = cur ^ 1;
      // copy-out chunk c addends (slot about to be refilled with c+2)
      const f32x4 cBA = pbA[cur], cBB = pbB[cur];
      float cMA[4], cMB[4];
#pragma unroll
      for (int r = 0; r < 4; ++r) { cMA[r] = pmA[cur][r]; cMB[r] = pmB[cur][r]; }
      // copy-out V(c-1) before its slot is refilled with V(c+1)
      const short8 vA = vf0[nxt], vB = vf1[nxt];
      // issue loads: bias/mask chunk c+2 (depth-2), V and K-frag chunk c+1
      if (c <= 8) {
        const int k2 = (c + 2) * 32;
        pbA[cur] = *(const f32x4*)(brow + k2 + lq * 4);
        pbB[cur] = *(const f32x4*)(brow + k2 + 16 + lq * 4);
#pragma unroll
        for (int r = 0; r < 4; ++r) {
          pmA[cur][r] = mrow[k2 + lq * 4 + r];
          const int kk = k2 + 16 + lq * 4 + r;
          pmB[cur][r] = mrow[(c == 8 && kk >= NTOK) ? 0 : kk];  // bias=-1e9 kills pad
        }
      }
      if (c <= 9) {
        const int k1 = (c + 1) * 32;
        vf0[nxt] = *(const short8*)(vrow0 + k1 + lq * 8);
        vf1[nxt] = *(const short8*)(vrow1 + k1 + lq * 8);
        kf0[nxt] = *(const short8*)(lds + (k1 + l15) * 80 + lq * 16);
        kf1[nxt] = *(const short8*)(lds + (k1 + 16 + l15) * 80 + lq * 16);
      }
      // read P(c-1) early (written last iter, same wave)
      short8 pf;
      if (c > 0) pf = *(const short8*)((nxt ? pb1 : pb0) + l15 * 80 + lq * 16);
      // swapped QK^T: D[k = lq*4+r (+16), q = l15]  (scale*log2e folded in q)
      f32x4 s0 = __builtin_amdgcn_mfma_f32_16x16x32_bf16(kf0[cur], aq, (f32x4)0.f, 0, 0, 0);
      f32x4 s1 = __builtin_amdgcn_mfma_f32_16x16x32_bf16(kf1[cur], aq, (f32x4)0.f, 0, 0, 0);
      float p0[4], p1[4], ps = 0.f;
#pragma unroll
      for (int r = 0; r < 4; ++r) {
        p0[r] = exp2f(s0[r] + fmaf(cMA[r], LOG2E, cBA[r]));
        p1[r] = exp2f(s1[r] + fmaf(cMB[r], LOG2E, cBB[r]));
        ps += p0[r] + p1[r];
      }
      l_run += ps;
      // pack P(c) (trunc bf16) -> LDS parity cur
      uint8_t* pw = (cur ? pb1 : pb0) + l15 * 80;
      *(uint2*)(pw + lq * 8)      = make_uint2(pk2bf(p0[0], p0[1]), pk2bf(p0[2], p0[3]));
      *(uint2*)(pw + 32 + lq * 8) = make_uint2(pk2bf(p1[0], p1[1]), pk2bf(p1[2], p1[3]));
      if (c > 0) {                  // deferred PV for chunk c-1
        o0 = __builtin_amdgcn_mfma_f32_16x16x32_bf16(pf, vA, o0, 0, 0, 0);
        o1 = __builtin_amdgcn_mfma_f32_16x16x32_bf16(pf, vB, o1, 0, 0, 0);
      }
    }
    {                               // PV for chunk 10 (parity 0; V(10) in slot 0)
      const short8 pf = *(const short8*)(pb0 + l15 * 80 + lq * 16);
      o0 = __builtin_amdgcn_mfma_f32_16x16x32_bf16(pf, vf0[0], o0, 0, 0, 0);
      o1 = __builtin_amdgcn_mfma_f32_16x16x32_bf16(pf, vf1[0], o1, 0, 0, 0);
    }
    // row-sum over 4 lq groups, broadcast to o-holder lanes (once per tile)
    l_run += __shfl_xor(l_run, 16);
    l_run += __shfl_xor(l_run, 32);
    const float invl = 1.f / l_run;
    float ir[4];
#pragma unroll
    for (int r = 0; r < 4; ++r) ir[r] = __shfl(invl, lq * 4 + r);
#pragma unroll
    for (int r = 0; r < 4; ++r) {
      const int q = q0 + lq * 4 + r;
      if (q < NTOK) {
        const size_t base = ((size_t)b * NTOK + q) * DIM + hh * 32 + 2 * l15;
        *(unsigned*)(out1 + base) =
            (((unsigned)f2bf(o1[r] * ir[r])) << 16) | f2bf(o0[r] * ir[r]);
      }
    }
  }
}

// ------------------------------- host launch --------------------------------
extern "C" void kernel_launch(void* const* d_in, const int* in_sizes, int n_in,
                              void* d_out, int out_size, void* d_ws, size_t ws_size,
                              hipStream_t stream) {
  const float* x      = (const float*)d_in[0];
  const float* mask   = (const float*)d_in[1];
  const float* qkv_w  = (const float*)d_in[2];
  const float* q_bias = (const float*)d_in[3];
  const float* v_bias = (const float*)d_in[4];
  const float* lsc    = (const float*)d_in[5];
  const float* cpb_w1 = (const float*)d_in[6];
  const float* cpb_b1 = (const float*)d_in[7];
  const float* cpb_w2 = (const float*)d_in[8];
  const float* proj_w = (const float*)d_in[9];
  const float* proj_b = (const float*)d_in[10];
  const float* rtab   = (const float*)d_in[11];
  const int*   ridx   = (const int*)d_in[12];
  float* out = (float*)d_out;
  uint8_t* ws = (uint8_t*)d_ws;

  size_t o = 0;
  auto alloc = [&](size_t bytes) { size_t r = o; o += (bytes + 255) & ~(size_t)255; return r; };
  const size_t off_xb  = alloc((size_t)MPAD * DIM * 2);   // also reused as o1b
  const size_t off_qwb = alloc((size_t)1152 * DIM * 2);
  const size_t off_pwb = alloc((size_t)DIM * DIM * 2);
  const size_t off_qnb = alloc((size_t)BW * HEADS * NTOK * 32 * 2);
  const size_t off_knb = alloc((size_t)BW * HEADS * NTOK * 32 * 2);
  const size_t off_vTb = alloc((size_t)BW * HEADS * 32 * NPAD * 2);
  const size_t off_btab  = alloc((size_t)2197 * 12 * 4);
  const size_t off_bfull = alloc((size_t)HEADS * NTOK * BPAD * 4);
  (void)in_sizes; (void)n_in; (void)out_size;

  if (ws_size < o) {   // diagnostic sentinel: clean fail (absmax ~= max|ref|)
    hipMemsetAsync(d_out, 0, (size_t)out_size * 4, stream);
    return;
  }

  unsigned short* xb  = (unsigned short*)(ws + off_xb);
  unsigned short* o1b = xb;                      // alias: xb dead after gemm<0>
  unsigned short* qwb = (unsigned short*)(ws + off_qwb);
  unsigned short* pwb = (unsigned short*)(ws + off_pwb);
  unsigned short* qnb = (unsigned short*)(ws + off_qnb);
  unsigned short* knb = (unsigned short*)(ws + off_knb);
  unsigned short* vTb = (unsigned short*)(ws + off_vTb);
  float* btab  = (float*)(ws + off_btab);
  float* bfull = (float*)(ws + off_bfull);

  cvt_bf16<<<(long)MPAD * DIM / 8 / 256, 256, 0, stream>>>(x, xb, (long)MROWS * DIM, (long)MPAD * DIM);
  cvt_bf16<<<1152 * DIM / 8 / 256, 256, 0, stream>>>(qkv_w, qwb, 1152L * DIM, 1152L * DIM);
  cvt_bf16<<<DIM * DIM / 8 / 256, 256, 0, stream>>>(proj_w, pwb, (long)DIM * DIM, (long)DIM * DIM);
  cpb_tab<<<2197, 64, 0, stream>>>(rtab, cpb_w1, cpb_b1, cpb_w2, btab);
  bias_gather<<<HEADS * NTOK, 256, 0, stream>>>(btab, ridx, bfull);
  gemm_k<0><<<dim3(MPAD / 128, 1152 / 128), 256, 0, stream>>>(
      xb, qwb, qnb, knb, vTb, q_bias, v_bias, lsc, nullptr, nullptr);
  attn_k<<<BW * HEADS, 256, 0, stream>>>(qnb, knb, vTb, bfull, mask, o1b);
  gemm_k<1><<<dim3(MPAD / 128, DIM / 128), 256, 0, stream>>>(
      o1b, pwb, nullptr, nullptr, nullptr, nullptr, nullptr, nullptr, out, proj_b);
}